// Round 4
// baseline (2997.907 us; speedup 1.0000x reference)
//
#include <hip/hip_runtime.h>
#include <cmath>

typedef unsigned short ushort_t;
typedef __attribute__((ext_vector_type(8))) short short8;
typedef __attribute__((ext_vector_type(4))) float f32x4;
typedef __attribute__((ext_vector_type(4))) short short4v;

static constexpr int NB = 2, NH = 8, NSEQ = 2048, DM = 1024, DH = 64, DI = 512;

__device__ __forceinline__ ushort_t f2b(float v) {
    unsigned u = __float_as_uint(v);
    return (ushort_t)((u + 0x7fffu + ((u >> 16) & 1u)) >> 16);  // RTNE
}
__device__ __forceinline__ float b2f(ushort_t b) { return __uint_as_float(((unsigned)b) << 16); }
__device__ __forceinline__ float sigm(float x) { return 1.f / (1.f + expf(-x)); }
__device__ __forceinline__ float silu(float x) { return x / (1.f + expf(-x)); }

#define MFMA16(a, b, c) __builtin_amdgcn_mfma_f32_16x16x32_bf16(a, b, c, 0, 0, 0)

// Direct global->VGPR MFMA fragment load from a row-major [., ld] bf16 matrix.
// Fragment (16 rows x 32 cols): lane l -> row row0+(l&15), cols col0+(l>>4)*8 .. +8.
__device__ __forceinline__ short8 gfrag(const ushort_t* __restrict__ base, int ld,
                                        int row0, int col0, int lane) {
    return *(const short8*)(base + (size_t)(row0 + (lane & 15)) * ld + col0 + ((lane >> 4) << 3));
}

__device__ __forceinline__ void mfma_hl(short8 ah, short8 al, short8 bh, short8 bl, f32x4& acc) {
    acc = MFMA16(ah, bh, acc);
    acc = MFMA16(ah, bl, acc);
    acc = MFMA16(al, bh, acc);
}

// ---- one-shot f32 -> bf16 hi(/lo) conversion ------------------------------------
__global__ __launch_bounds__(256) void k_cvt(const float4* __restrict__ src,
                                             ushort_t* __restrict__ hi,
                                             ushort_t* __restrict__ lo, int n4, int has_lo) {
    for (int i = blockIdx.x * 256 + threadIdx.x; i < n4; i += gridDim.x * 256) {
        float4 f = src[i];
        float a[4] = {f.x, f.y, f.z, f.w};
        short4v hv, lv;
#pragma unroll
        for (int j = 0; j < 4; ++j) {
            ushort_t h = f2b(a[j]);
            hv[j] = (short)h;
            lv[j] = (short)f2b(a[j] - b2f(h));
        }
        *(short4v*)(hi + (size_t)i * 4) = hv;
        if (has_lo) *(short4v*)(lo + (size_t)i * 4) = lv;
    }
}

// ---- proj: qkv = x @ Wqkv^T (hi/lo direct frags), scatter + vcT -----------------
__global__ __launch_bounds__(256) void k_proj(const ushort_t* __restrict__ xh,
                                              const ushort_t* __restrict__ xl,
                                              const ushort_t* __restrict__ wh,
                                              const ushort_t* __restrict__ wl,
                                              ushort_t* __restrict__ qh, ushort_t* __restrict__ ql,
                                              ushort_t* __restrict__ vcT) {
    f32x4 acc[4][4] = {};
    const int m0 = blockIdx.y * 128, n0 = blockIdx.x * 128;
    const int l = threadIdx.x & 63, w = threadIdx.x >> 6;
    const int mb = m0 + (w >> 1) * 64, nb = n0 + (w & 1) * 64;
    for (int k0 = 0; k0 < DM; k0 += 32) {
        short8 ah[4], al[4], bh[4], bl[4];
#pragma unroll
        for (int i = 0; i < 4; ++i) {
            ah[i] = gfrag(xh, DM, mb + i * 16, k0, l);
            al[i] = gfrag(xl, DM, mb + i * 16, k0, l);
            bh[i] = gfrag(wh, DM, nb + i * 16, k0, l);
            bl[i] = gfrag(wl, DM, nb + i * 16, k0, l);
        }
#pragma unroll
        for (int i = 0; i < 4; ++i)
#pragma unroll
            for (int j = 0; j < 4; ++j) mfma_hl(ah[i], al[i], bh[j], bl[j], acc[i][j]);
    }
#pragma unroll
    for (int i = 0; i < 4; ++i)
#pragma unroll
        for (int j = 0; j < 4; ++j)
#pragma unroll
            for (int r = 0; r < 4; ++r) {
                int m = mb + i * 16 + (l >> 4) * 4 + r;
                int n = nb + j * 16 + (l & 15);
                float v = acc[i][j][r];
                int t = n >> 9, head = (n >> 6) & 7, dd = n & 63;
                int b = m >> 11, np = m & 2047;
                if (t == 0 || t == 3) v *= 0.125f;
                ushort_t h = f2b(v), lo = f2b(v - b2f(h));
                size_t off = (size_t)(t * 16 + b * 8 + head) * 131072 + (size_t)np * 64 + dd;
                qh[off] = h;
                ql[off] = lo;
                if (t == 5) vcT[(size_t)(b * 8 + head) * 131072 + (size_t)dd * 2048 + np] = h;
            }
}

// ---- t1 = mask_lower(qc_s @ vu^T), hi/lo, direct frags --------------------------
__global__ __launch_bounds__(256) void k_t1(const ushort_t* __restrict__ qh,
                                            const ushort_t* __restrict__ ql,
                                            ushort_t* __restrict__ t1h, ushort_t* __restrict__ t1l,
                                            int g0) {
    const int bxj = blockIdx.x, byi = blockIdx.y;
    if (bxj > byi) return;
    const int z = blockIdx.z, hh = g0 + z;
    const ushort_t* qch = qh + (size_t)(3 * 16 + hh) * 131072;
    const ushort_t* qcl = ql + (size_t)(3 * 16 + hh) * 131072;
    const ushort_t* vuh = qh + (size_t)(2 * 16 + hh) * 131072;
    const ushort_t* vul = ql + (size_t)(2 * 16 + hh) * 131072;
    f32x4 acc[4][4] = {};
    const int l = threadIdx.x & 63, w = threadIdx.x >> 6;
    const int mb = byi * 128 + (w >> 1) * 64, nb = bxj * 128 + (w & 1) * 64;
#pragma unroll
    for (int k0 = 0; k0 < DH; k0 += 32) {
        short8 ah[4], al[4], bh[4], bl[4];
#pragma unroll
        for (int i = 0; i < 4; ++i) {
            ah[i] = gfrag(qch, DH, mb + i * 16, k0, l);
            al[i] = gfrag(qcl, DH, mb + i * 16, k0, l);
            bh[i] = gfrag(vuh, DH, nb + i * 16, k0, l);
            bl[i] = gfrag(vul, DH, nb + i * 16, k0, l);
        }
#pragma unroll
        for (int i = 0; i < 4; ++i)
#pragma unroll
            for (int j = 0; j < 4; ++j) mfma_hl(ah[i], al[i], bh[j], bl[j], acc[i][j]);
    }
    ushort_t* th = t1h + (size_t)z * 4194304;
    ushort_t* tl = t1l + (size_t)z * 4194304;
#pragma unroll
    for (int i = 0; i < 4; ++i)
#pragma unroll
        for (int j = 0; j < 4; ++j)
#pragma unroll
            for (int r = 0; r < 4; ++r) {
                int gi = mb + i * 16 + (l >> 4) * 4 + r;
                int gj = nb + j * 16 + (l & 15);
                float v = (gj <= gi) ? acc[i][j][r] : 0.f;
                ushort_t h = f2b(v), lo = f2b(v - b2f(h));
                th[(size_t)gi * 2048 + gj] = h;
                tl[(size_t)gi * 2048 + gj] = lo;
            }
}

// ---- look = mask_strict_upper(sigmoid(qu_s @ ku^T)), hi/lo ----------------------
__global__ __launch_bounds__(256) void k_look(const ushort_t* __restrict__ qh,
                                              const ushort_t* __restrict__ ql,
                                              ushort_t* __restrict__ lkh,
                                              ushort_t* __restrict__ lkl, int g0) {
    const int bxj = blockIdx.x, byk = blockIdx.y;
    if (bxj < byk) return;
    const int z = blockIdx.z, hh = g0 + z;
    const ushort_t* quh = qh + (size_t)(0 * 16 + hh) * 131072;
    const ushort_t* qul = ql + (size_t)(0 * 16 + hh) * 131072;
    const ushort_t* kuh = qh + (size_t)(1 * 16 + hh) * 131072;
    const ushort_t* kul = ql + (size_t)(1 * 16 + hh) * 131072;
    f32x4 acc[4][4] = {};
    const int l = threadIdx.x & 63, w = threadIdx.x >> 6;
    const int mb = byk * 128 + (w >> 1) * 64, nb = bxj * 128 + (w & 1) * 64;
#pragma unroll
    for (int k0 = 0; k0 < DH; k0 += 32) {
        short8 ah[4], al[4], bh[4], bl[4];
#pragma unroll
        for (int i = 0; i < 4; ++i) {
            ah[i] = gfrag(quh, DH, mb + i * 16, k0, l);
            al[i] = gfrag(qul, DH, mb + i * 16, k0, l);
            bh[i] = gfrag(kuh, DH, nb + i * 16, k0, l);
            bl[i] = gfrag(kul, DH, nb + i * 16, k0, l);
        }
#pragma unroll
        for (int i = 0; i < 4; ++i)
#pragma unroll
            for (int j = 0; j < 4; ++j) mfma_hl(ah[i], al[i], bh[j], bl[j], acc[i][j]);
    }
    ushort_t* lh = lkh + (size_t)z * 4194304;
    ushort_t* ll = lkl + (size_t)z * 4194304;
#pragma unroll
    for (int i = 0; i < 4; ++i)
#pragma unroll
        for (int j = 0; j < 4; ++j)
#pragma unroll
            for (int r = 0; r < 4; ++r) {
                int gk = mb + i * 16 + (l >> 4) * 4 + r;
                int gj = nb + j * 16 + (l & 15);
                float v = (gj > gk) ? sigm(acc[i][j][r]) : 0.f;
                ushort_t h = f2b(v), lo = f2b(v - b2f(h));
                lh[(size_t)gk * 2048 + gj] = h;
                ll[(size_t)gk * 2048 + gj] = lo;
            }
}

// ---- scores = qc_s@kc^T - silu(t1 @ look^T), fp32 out (k<=i) --------------------
__global__ __launch_bounds__(256) void k_scores(const ushort_t* __restrict__ t1h,
                                                const ushort_t* __restrict__ t1l,
                                                const ushort_t* __restrict__ lkh,
                                                const ushort_t* __restrict__ lkl,
                                                const ushort_t* __restrict__ qh,
                                                const ushort_t* __restrict__ ql,
                                                float* __restrict__ sc, int g0) {
    const int bxk = blockIdx.x, byi = blockIdx.y;
    if (bxk > byi) return;
    const int z = blockIdx.z, hh = g0 + z;
    const ushort_t* th = t1h + (size_t)z * 4194304;
    const ushort_t* tl = t1l + (size_t)z * 4194304;
    const ushort_t* lh = lkh + (size_t)z * 4194304;
    const ushort_t* ll = lkl + (size_t)z * 4194304;
    f32x4 acc[4][4] = {};
    const int l = threadIdx.x & 63, w = threadIdx.x >> 6;
    const int mb = byi * 128 + (w >> 1) * 64, nb = bxk * 128 + (w & 1) * 64;
    const int jend = (byi + 1) * 128;
    for (int j0 = bxk * 128; j0 < jend; j0 += 32) {
        short8 ah[4], al[4], bh[4], bl[4];
#pragma unroll
        for (int i = 0; i < 4; ++i) {
            ah[i] = gfrag(th, 2048, mb + i * 16, j0, l);
            al[i] = gfrag(tl, 2048, mb + i * 16, j0, l);
            bh[i] = gfrag(lh, 2048, nb + i * 16, j0, l);
            bl[i] = gfrag(ll, 2048, nb + i * 16, j0, l);
        }
#pragma unroll
        for (int i = 0; i < 4; ++i)
#pragma unroll
            for (int j = 0; j < 4; ++j) mfma_hl(ah[i], al[i], bh[j], bl[j], acc[i][j]);
    }
#pragma unroll
    for (int i = 0; i < 4; ++i)
#pragma unroll
        for (int j = 0; j < 4; ++j)
#pragma unroll
            for (int r = 0; r < 4; ++r) acc[i][j][r] = -silu(acc[i][j][r]);
    const ushort_t* qch = qh + (size_t)(3 * 16 + hh) * 131072;
    const ushort_t* qcl = ql + (size_t)(3 * 16 + hh) * 131072;
    const ushort_t* kch = qh + (size_t)(4 * 16 + hh) * 131072;
    const ushort_t* kcl = ql + (size_t)(4 * 16 + hh) * 131072;
#pragma unroll
    for (int k0 = 0; k0 < DH; k0 += 32) {
        short8 ah[4], al[4], bh[4], bl[4];
#pragma unroll
        for (int i = 0; i < 4; ++i) {
            ah[i] = gfrag(qch, DH, mb + i * 16, k0, l);
            al[i] = gfrag(qcl, DH, mb + i * 16, k0, l);
            bh[i] = gfrag(kch, DH, nb + i * 16, k0, l);
            bl[i] = gfrag(kcl, DH, nb + i * 16, k0, l);
        }
#pragma unroll
        for (int i = 0; i < 4; ++i)
#pragma unroll
            for (int j = 0; j < 4; ++j) mfma_hl(ah[i], al[i], bh[j], bl[j], acc[i][j]);
    }
    float* so = sc + (size_t)z * 4194304;
#pragma unroll
    for (int i = 0; i < 4; ++i)
#pragma unroll
        for (int j = 0; j < 4; ++j)
#pragma unroll
            for (int r = 0; r < 4; ++r) {
                int gi = mb + i * 16 + (l >> 4) * 4 + r;
                int gk = nb + j * 16 + (l & 15);
                if (gk <= gi) so[(size_t)gi * 2048 + gk] = acc[i][j][r];
            }
}

// ---- row softmax (k<=i) -> bf16 attn --------------------------------------------
__global__ __launch_bounds__(256) void k_softmax(const float* __restrict__ sc,
                                                 ushort_t* __restrict__ attn) {
    const int z = blockIdx.x >> 11, i = blockIdx.x & 2047;
    const float* row = sc + ((size_t)z * 2048 + i) * 2048;
    const float4* row4 = (const float4*)row;
    ushort_t* arow = attn + ((size_t)z * 2048 + i) * 2048;
    const int nv = i + 1, nv4 = nv >> 2, tid = threadIdx.x;
    __shared__ float red[256];
    float m = -INFINITY;
    for (int k = tid; k < nv4; k += 256) {
        float4 f = row4[k];
        m = fmaxf(fmaxf(fmaxf(m, f.x), fmaxf(f.y, f.z)), f.w);
    }
    for (int k = nv4 * 4 + tid; k < nv; k += 256) m = fmaxf(m, row[k]);
    red[tid] = m;
    __syncthreads();
    for (int s = 128; s; s >>= 1) {
        if (tid < s) red[tid] = fmaxf(red[tid], red[tid + s]);
        __syncthreads();
    }
    m = red[0];
    __syncthreads();
    float sum = 0.f;
    for (int k = tid; k < nv4; k += 256) {
        float4 f = row4[k];
        sum += expf(f.x - m) + expf(f.y - m) + expf(f.z - m) + expf(f.w - m);
    }
    for (int k = nv4 * 4 + tid; k < nv; k += 256) sum += expf(row[k] - m);
    red[tid] = sum;
    __syncthreads();
    for (int s = 128; s; s >>= 1) {
        if (tid < s) red[tid] += red[tid + s];
        __syncthreads();
    }
    const float inv = 1.f / red[0];
    for (int k = tid; k < nv4; k += 256) {
        float4 f = row4[k];
        short4v o;
        o[0] = (short)f2b(expf(f.x - m) * inv);
        o[1] = (short)f2b(expf(f.y - m) * inv);
        o[2] = (short)f2b(expf(f.z - m) * inv);
        o[3] = (short)f2b(expf(f.w - m) * inv);
        *(short4v*)(arow + k * 4) = o;
    }
    for (int k = nv4 * 4 + tid; k < nv; k += 256) arow[k] = f2b(expf(row[k] - m) * inv);
    for (int k = nv + tid; k < 2048; k += 256) arow[k] = 0;
}

// ---- pv: attno = attn @ vc (via vcT), direct frags ------------------------------
__global__ __launch_bounds__(256) void k_pv(const ushort_t* __restrict__ attn,
                                            const ushort_t* __restrict__ vcT,
                                            ushort_t* __restrict__ attno, int g0) {
    const int byi = blockIdx.x, z = blockIdx.y, hh = g0 + z;
    const int b = hh >> 3, h = hh & 7;
    f32x4 acc[2][4] = {};
    const int l = threadIdx.x & 63, w = threadIdx.x >> 6;
    const int mb = byi * 128 + w * 32;
    const ushort_t* ap = attn + (size_t)z * 4194304;
    const ushort_t* vp = vcT + (size_t)hh * 131072;
    const int kend = (byi + 1) * 128;
    for (int k0 = 0; k0 < kend; k0 += 32) {
        short8 a[2], bfr[4];
#pragma unroll
        for (int i = 0; i < 2; ++i) a[i] = gfrag(ap, 2048, mb + i * 16, k0, l);
#pragma unroll
        for (int j = 0; j < 4; ++j) bfr[j] = gfrag(vp, 2048, j * 16, k0, l);
#pragma unroll
        for (int i = 0; i < 2; ++i)
#pragma unroll
            for (int j = 0; j < 4; ++j) acc[i][j] = MFMA16(a[i], bfr[j], acc[i][j]);
    }
#pragma unroll
    for (int i = 0; i < 2; ++i)
#pragma unroll
        for (int j = 0; j < 4; ++j)
#pragma unroll
            for (int r = 0; r < 4; ++r) {
                int gi = mb + i * 16 + (l >> 4) * 4 + r;
                int d = j * 16 + (l & 15);
                attno[((size_t)(b * 2048 + gi)) * 512 + h * 64 + d] = f2b(acc[i][j][r]);
            }
}

// ---- final = attno @ Wout^T, direct frags ---------------------------------------
__global__ __launch_bounds__(256) void k_outproj(const ushort_t* __restrict__ attno,
                                                 const ushort_t* __restrict__ woh,
                                                 float* __restrict__ out) {
    f32x4 acc[4][4] = {};
    const int m0 = blockIdx.y * 128, n0 = blockIdx.x * 128;
    const int l = threadIdx.x & 63, w = threadIdx.x >> 6;
    const int mb = m0 + (w >> 1) * 64, nb = n0 + (w & 1) * 64;
    for (int k0 = 0; k0 < DI; k0 += 32) {
        short8 a[4], bfr[4];
#pragma unroll
        for (int i = 0; i < 4; ++i) {
            a[i] = gfrag(attno, DI, mb + i * 16, k0, l);
            bfr[i] = gfrag(woh, DI, nb + i * 16, k0, l);
        }
#pragma unroll
        for (int i = 0; i < 4; ++i)
#pragma unroll
            for (int j = 0; j < 4; ++j) acc[i][j] = MFMA16(a[i], bfr[j], acc[i][j]);
    }
#pragma unroll
    for (int i = 0; i < 4; ++i)
#pragma unroll
        for (int j = 0; j < 4; ++j)
#pragma unroll
            for (int r = 0; r < 4; ++r) {
                int m = mb + i * 16 + (l >> 4) * 4 + r;
                int n = nb + j * 16 + (l & 15);
                out[(size_t)m * DM + n] = acc[i][j][r];
            }
}

extern "C" void kernel_launch(void* const* d_in, const int* in_sizes, int n_in,
                              void* d_out, int out_size, void* d_ws, size_t ws_size,
                              hipStream_t stream) {
    const float* x = (const float*)d_in[0];
    const float* Wqkv = (const float*)d_in[1];
    const float* Wout = (const float*)d_in[2];
    float* out = (float*)d_out;

    // element counts
    const size_t xel = (size_t)4096 * 1024;   // 4,194,304
    const size_t wel = (size_t)3072 * 1024;   // 3,145,728
    const size_t woel = (size_t)1024 * 512;   // 524,288
    const size_t qel = 12582912, vel = 2097152, ael = 2097152;
    const size_t nn = 4194304;

    const size_t fixed_el = 2 * xel + 2 * wel + woel + 2 * qel + vel + ael;  // bf16 elems
    const size_t per_el = 4 * nn + 2 * nn;  // t1 h/l + lk h/l + sc(f32 = 2x bf16 elems)
    int g = 0;
    for (int cand : {16, 8, 4, 2, 1})
        if ((fixed_el + per_el * (size_t)cand) * 2 <= ws_size) { g = cand; break; }
    if (!g) return;

    ushort_t* xh = (ushort_t*)d_ws;
    ushort_t* xl = xh + xel;
    ushort_t* wh = xl + xel;
    ushort_t* wl = wh + wel;
    ushort_t* woh = wl + wel;
    ushort_t* qh = woh + woel;
    ushort_t* ql = qh + qel;
    ushort_t* vcT = ql + qel;
    ushort_t* attno = vcT + vel;
    ushort_t* t1h = attno + ael;
    ushort_t* t1l = t1h + (size_t)g * nn;
    ushort_t* lkh = t1l + (size_t)g * nn;
    ushort_t* lkl = lkh + (size_t)g * nn;
    float* scb = (float*)(lkl + (size_t)g * nn);

    k_cvt<<<dim3(1024), 256, 0, stream>>>((const float4*)x, xh, xl, (int)(xel / 4), 1);
    k_cvt<<<dim3(1024), 256, 0, stream>>>((const float4*)Wqkv, wh, wl, (int)(wel / 4), 1);
    k_cvt<<<dim3(512), 256, 0, stream>>>((const float4*)Wout, woh, nullptr, (int)(woel / 4), 0);

    k_proj<<<dim3(24, 32), 256, 0, stream>>>(xh, xl, wh, wl, qh, ql, vcT);

    for (int g0 = 0; g0 < 16; g0 += g) {
        dim3 grid(16, 16, g);
        k_t1<<<grid, 256, 0, stream>>>(qh, ql, t1h, t1l, g0);
        k_look<<<grid, 256, 0, stream>>>(qh, ql, lkh, lkl, g0);
        k_scores<<<grid, 256, 0, stream>>>(t1h, t1l, lkh, lkl, qh, ql, scb, g0);
        k_softmax<<<dim3(2048 * g), 256, 0, stream>>>(scb, t1h);
        k_pv<<<dim3(16, g), 256, 0, stream>>>(t1h, vcT, attno, g0);
    }

    k_outproj<<<dim3(8, 32), 256, 0, stream>>>(attno, woh, out);
}

// Round 5
// 1110.518 us; speedup vs baseline: 2.6996x; 2.6996x over previous
//
#include <hip/hip_runtime.h>
#include <cmath>

typedef unsigned short ushort_t;
typedef __attribute__((ext_vector_type(8))) short short8;
typedef __attribute__((ext_vector_type(4))) float f32x4;
typedef __attribute__((ext_vector_type(4))) short short4v;

static constexpr int NSEQ = 2048, DM = 1024, DH = 64, DI = 512;

__device__ __forceinline__ ushort_t f2b(float v) {
    unsigned u = __float_as_uint(v);
    return (ushort_t)((u + 0x7fffu + ((u >> 16) & 1u)) >> 16);  // RTNE
}
__device__ __forceinline__ float b2f(ushort_t b) { return __uint_as_float(((unsigned)b) << 16); }
__device__ __forceinline__ float sigm(float x) { return 1.f / (1.f + expf(-x)); }
__device__ __forceinline__ float silu(float x) { return x / (1.f + expf(-x)); }

#define MFMA16(a, b, c) __builtin_amdgcn_mfma_f32_16x16x32_bf16(a, b, c, 0, 0, 0)

// Swizzled LDS tile: [rows][32 bf16] pitch 32, 16B-chunk c swizzled by row.
// Both ds_write and ds_read_b128 patterns hit the 8-words/bank floor.
__device__ __forceinline__ int swz_off(int row, int c) {
    return row * 32 + ((c ^ ((row >> 1) & 3)) << 3);
}
__device__ __forceinline__ short8 sfrag(const ushort_t* t, int row0, int lane) {
    const int row = row0 + (lane & 15);
    return *(const short8*)(t + swz_off(row, lane >> 4));
}

// ---- hi/lo staging (A,B both 128x32): regs <-> global / LDS --------------------
struct SHL { short8 v[8]; };
__device__ __forceinline__ void ldhl(const ushort_t* ah, const ushort_t* al,
                                     const ushort_t* bh, const ushort_t* bl,
                                     int lda, int ldb, SHL& s) {
    const int tid = threadIdx.x, row = tid >> 1, c0 = (tid & 1) * 2;
    const size_t oa = (size_t)row * lda + c0 * 8;
    const size_t ob = (size_t)row * ldb + c0 * 8;
    s.v[0] = *(const short8*)(ah + oa); s.v[1] = *(const short8*)(ah + oa + 8);
    s.v[2] = *(const short8*)(al + oa); s.v[3] = *(const short8*)(al + oa + 8);
    s.v[4] = *(const short8*)(bh + ob); s.v[5] = *(const short8*)(bh + ob + 8);
    s.v[6] = *(const short8*)(bl + ob); s.v[7] = *(const short8*)(bl + ob + 8);
}
__device__ __forceinline__ void sthl(ushort_t* buf, const SHL& s) {
    const int tid = threadIdx.x, row = tid >> 1, c0 = (tid & 1) * 2;
    const int o0 = swz_off(row, c0), o1 = swz_off(row, c0 + 1);
    *(short8*)(buf + o0) = s.v[0];         *(short8*)(buf + o1) = s.v[1];
    *(short8*)(buf + 4096 + o0) = s.v[2];  *(short8*)(buf + 4096 + o1) = s.v[3];
    *(short8*)(buf + 8192 + o0) = s.v[4];  *(short8*)(buf + 8192 + o1) = s.v[5];
    *(short8*)(buf + 12288 + o0) = s.v[6]; *(short8*)(buf + 12288 + o1) = s.v[7];
}
__device__ __forceinline__ void mm_hl(const ushort_t* buf, int mb, int nb, int lane,
                                      f32x4 (&acc)[4][4]) {
    short8 fah[4], fal[4], fbh[4], fbl[4];
#pragma unroll
    for (int i = 0; i < 4; ++i) {
        fah[i] = sfrag(buf, mb + i * 16, lane);
        fal[i] = sfrag(buf + 4096, mb + i * 16, lane);
    }
#pragma unroll
    for (int j = 0; j < 4; ++j) {
        fbh[j] = sfrag(buf + 8192, nb + j * 16, lane);
        fbl[j] = sfrag(buf + 12288, nb + j * 16, lane);
    }
#pragma unroll
    for (int i = 0; i < 4; ++i)
#pragma unroll
        for (int j = 0; j < 4; ++j) {
            acc[i][j] = MFMA16(fah[i], fbh[j], acc[i][j]);
            acc[i][j] = MFMA16(fah[i], fbl[j], acc[i][j]);
            acc[i][j] = MFMA16(fal[i], fbh[j], acc[i][j]);
        }
}

// ---- one-shot f32 -> bf16 hi(/lo) -----------------------------------------------
__global__ __launch_bounds__(256) void k_cvt(const float4* __restrict__ src,
                                             ushort_t* __restrict__ hi,
                                             ushort_t* __restrict__ lo, int n4, int has_lo) {
    for (int i = blockIdx.x * 256 + threadIdx.x; i < n4; i += gridDim.x * 256) {
        float4 f = src[i];
        float a[4] = {f.x, f.y, f.z, f.w};
        short4v hv, lv;
#pragma unroll
        for (int j = 0; j < 4; ++j) {
            ushort_t h = f2b(a[j]);
            hv[j] = (short)h;
            lv[j] = (short)f2b(a[j] - b2f(h));
        }
        *(short4v*)(hi + (size_t)i * 4) = hv;
        if (has_lo) *(short4v*)(lo + (size_t)i * 4) = lv;
    }
}

// ---- proj: qkv = x @ Wqkv^T, pipelined hi/lo, scatter + vcT ---------------------
__global__ __launch_bounds__(256) void k_proj(const ushort_t* __restrict__ xh,
                                              const ushort_t* __restrict__ xl,
                                              const ushort_t* __restrict__ wh,
                                              const ushort_t* __restrict__ wl,
                                              ushort_t* __restrict__ qh, ushort_t* __restrict__ ql,
                                              ushort_t* __restrict__ vcT) {
    __shared__ __align__(16) ushort_t lds[2][16384];
    const int m0 = blockIdx.y * 128, n0 = blockIdx.x * 128;
    const int l = threadIdx.x & 63, w = threadIdx.x >> 6;
    const int mb = (w >> 1) * 64, nb = (w & 1) * 64;
    const ushort_t* pa_h = xh + (size_t)m0 * DM;
    const ushort_t* pa_l = xl + (size_t)m0 * DM;
    const ushort_t* pb_h = wh + (size_t)n0 * DM;
    const ushort_t* pb_l = wl + (size_t)n0 * DM;
    SHL s;
    ldhl(pa_h, pa_l, pb_h, pb_l, DM, DM, s);
    f32x4 acc[4][4] = {};
    for (int t = 0; t < 32; ++t) {
        ushort_t* buf = lds[t & 1];
        sthl(buf, s);
        __syncthreads();
        if (t + 1 < 32) {
            int k0 = (t + 1) * 32;
            ldhl(pa_h + k0, pa_l + k0, pb_h + k0, pb_l + k0, DM, DM, s);
        }
        mm_hl(buf, mb, nb, l, acc);
    }
#pragma unroll
    for (int i = 0; i < 4; ++i)
#pragma unroll
        for (int j = 0; j < 4; ++j)
#pragma unroll
            for (int r = 0; r < 4; ++r) {
                int m = m0 + mb + i * 16 + (l >> 4) * 4 + r;
                int n = n0 + nb + j * 16 + (l & 15);
                float v = acc[i][j][r];
                int tt = n >> 9, head = (n >> 6) & 7, dd = n & 63;
                int b = m >> 11, np = m & 2047;
                if (tt == 0 || tt == 3) v *= 0.125f;
                ushort_t h = f2b(v), lo = f2b(v - b2f(h));
                size_t off = (size_t)(tt * 16 + b * 8 + head) * 131072 + (size_t)np * 64 + dd;
                qh[off] = h;
                ql[off] = lo;
                if (tt == 5) vcT[(size_t)(b * 8 + head) * 131072 + (size_t)dd * 2048 + np] = h;
            }
}

// ---- t1 + look merged, pipelined (K=64), z = head*2 + which ---------------------
__global__ __launch_bounds__(256) void k_tl(const ushort_t* __restrict__ qkvh,
                                            const ushort_t* __restrict__ qkvl,
                                            ushort_t* __restrict__ t1h, ushort_t* __restrict__ t1l,
                                            ushort_t* __restrict__ lkh, ushort_t* __restrict__ lkl,
                                            int g0) {
    const int bx = blockIdx.x, by = blockIdx.y;
    const int which = blockIdx.z & 1, z = blockIdx.z >> 1, hh = g0 + z;
    if (which == 0 ? (bx > by) : (bx < by)) return;
    const int ta = which ? 0 : 3, tb = which ? 1 : 2;
    const ushort_t* ah = qkvh + (size_t)(ta * 16 + hh) * 131072 + (size_t)(by * 128) * 64;
    const ushort_t* al = qkvl + (size_t)(ta * 16 + hh) * 131072 + (size_t)(by * 128) * 64;
    const ushort_t* bh = qkvh + (size_t)(tb * 16 + hh) * 131072 + (size_t)(bx * 128) * 64;
    const ushort_t* bl = qkvl + (size_t)(tb * 16 + hh) * 131072 + (size_t)(bx * 128) * 64;
    __shared__ __align__(16) ushort_t lds[2][16384];
    const int l = threadIdx.x & 63, w = threadIdx.x >> 6;
    const int mb = (w >> 1) * 64, nb = (w & 1) * 64;
    SHL s;
    ldhl(ah, al, bh, bl, DH, DH, s);
    f32x4 acc[4][4] = {};
    for (int t = 0; t < 2; ++t) {
        ushort_t* buf = lds[t & 1];
        sthl(buf, s);
        __syncthreads();
        if (t == 0) ldhl(ah + 32, al + 32, bh + 32, bl + 32, DH, DH, s);
        mm_hl(buf, mb, nb, l, acc);
    }
    if (which == 0) {
        ushort_t* th = t1h + (size_t)z * 4194304;
        ushort_t* tl = t1l + (size_t)z * 4194304;
#pragma unroll
        for (int i = 0; i < 4; ++i)
#pragma unroll
            for (int j = 0; j < 4; ++j)
#pragma unroll
                for (int r = 0; r < 4; ++r) {
                    int gi = by * 128 + mb + i * 16 + (l >> 4) * 4 + r;
                    int gj = bx * 128 + nb + j * 16 + (l & 15);
                    float v = (gj <= gi) ? acc[i][j][r] : 0.f;
                    ushort_t h = f2b(v), lo = f2b(v - b2f(h));
                    th[(size_t)gi * 2048 + gj] = h;
                    tl[(size_t)gi * 2048 + gj] = lo;
                }
    } else {
        ushort_t* lh = lkh + (size_t)z * 4194304;
        ushort_t* ll = lkl + (size_t)z * 4194304;
#pragma unroll
        for (int i = 0; i < 4; ++i)
#pragma unroll
            for (int j = 0; j < 4; ++j)
#pragma unroll
                for (int r = 0; r < 4; ++r) {
                    int gk = by * 128 + mb + i * 16 + (l >> 4) * 4 + r;
                    int gj = bx * 128 + nb + j * 16 + (l & 15);
                    float v = (gj > gk) ? sigm(acc[i][j][r]) : 0.f;
                    ushort_t h = f2b(v), lo = f2b(v - b2f(h));
                    lh[(size_t)gk * 2048 + gj] = h;
                    ll[(size_t)gk * 2048 + gj] = lo;
                }
    }
}

// ---- scores = qc_s@kc^T - silu(t1 @ look^T), pipelined, fp32 out ----------------
__global__ __launch_bounds__(256) void k_scores(const ushort_t* __restrict__ t1h,
                                                const ushort_t* __restrict__ t1l,
                                                const ushort_t* __restrict__ lkh,
                                                const ushort_t* __restrict__ lkl,
                                                const ushort_t* __restrict__ qkvh,
                                                const ushort_t* __restrict__ qkvl,
                                                float* __restrict__ sc, int g0) {
    const int bxk = blockIdx.x, byi = blockIdx.y;
    if (bxk > byi) return;
    const int z = blockIdx.z, hh = g0 + z;
    __shared__ __align__(16) ushort_t lds[2][16384];
    const int l = threadIdx.x & 63, w = threadIdx.x >> 6;
    const int mb = (w >> 1) * 64, nb = (w & 1) * 64;
    const int nsu = (byi - bxk + 1) * 4, nt = nsu + 2;
    const ushort_t* th = t1h + (size_t)z * 4194304 + (size_t)(byi * 128) * 2048;
    const ushort_t* tl = t1l + (size_t)z * 4194304 + (size_t)(byi * 128) * 2048;
    const ushort_t* lh = lkh + (size_t)z * 4194304 + (size_t)(bxk * 128) * 2048;
    const ushort_t* ll = lkl + (size_t)z * 4194304 + (size_t)(bxk * 128) * 2048;
    const ushort_t* qch = qkvh + (size_t)(3 * 16 + hh) * 131072 + (size_t)(byi * 128) * 64;
    const ushort_t* qcl = qkvl + (size_t)(3 * 16 + hh) * 131072 + (size_t)(byi * 128) * 64;
    const ushort_t* kch = qkvh + (size_t)(4 * 16 + hh) * 131072 + (size_t)(bxk * 128) * 64;
    const ushort_t* kcl = qkvl + (size_t)(4 * 16 + hh) * 131072 + (size_t)(bxk * 128) * 64;

    SHL s;
    {   // t = 0 (always Su phase)
        int j0 = bxk * 128;
        ldhl(th + j0, tl + j0, lh + j0, ll + j0, 2048, 2048, s);
    }
    f32x4 acc[4][4] = {};
    for (int t = 0; t < nt; ++t) {
        ushort_t* buf = lds[t & 1];
        sthl(buf, s);
        __syncthreads();
        const int tn = t + 1;
        if (tn < nt) {
            if (tn < nsu) {
                int j0 = bxk * 128 + tn * 32;
                ldhl(th + j0, tl + j0, lh + j0, ll + j0, 2048, 2048, s);
            } else {
                int k0 = (tn - nsu) * 32;
                ldhl(qch + k0, qcl + k0, kch + k0, kcl + k0, 64, 64, s);
            }
        }
        if (t == nsu) {
#pragma unroll
            for (int i = 0; i < 4; ++i)
#pragma unroll
                for (int j = 0; j < 4; ++j)
#pragma unroll
                    for (int r = 0; r < 4; ++r) acc[i][j][r] = -silu(acc[i][j][r]);
        }
        mm_hl(buf, mb, nb, l, acc);
    }
    float* so = sc + (size_t)z * 4194304;
#pragma unroll
    for (int i = 0; i < 4; ++i)
#pragma unroll
        for (int j = 0; j < 4; ++j)
#pragma unroll
            for (int r = 0; r < 4; ++r) {
                int gi = byi * 128 + mb + i * 16 + (l >> 4) * 4 + r;
                int gk = bxk * 128 + nb + j * 16 + (l & 15);
                if (gk <= gi) so[(size_t)gi * 2048 + gk] = acc[i][j][r];
            }
}

// ---- row softmax (k<=i) -> bf16 attn (into t1h), zero-pad to 128 ----------------
__global__ __launch_bounds__(256) void k_softmax(const float* __restrict__ sc,
                                                 ushort_t* __restrict__ attn) {
    const int z = blockIdx.x >> 11, i = blockIdx.x & 2047;
    const float* row = sc + ((size_t)z * 2048 + i) * 2048;
    const float4* row4 = (const float4*)row;
    ushort_t* arow = attn + (size_t)z * 4194304 + (size_t)i * 2048;
    const int nv = i + 1, nv4 = nv >> 2, tid = threadIdx.x;
    __shared__ float red[256];
    float m = -INFINITY;
    for (int k = tid; k < nv4; k += 256) {
        float4 f = row4[k];
        m = fmaxf(fmaxf(fmaxf(m, f.x), fmaxf(f.y, f.z)), f.w);
    }
    for (int k = nv4 * 4 + tid; k < nv; k += 256) m = fmaxf(m, row[k]);
    red[tid] = m;
    __syncthreads();
    for (int ss = 128; ss; ss >>= 1) {
        if (tid < ss) red[tid] = fmaxf(red[tid], red[tid + ss]);
        __syncthreads();
    }
    m = red[0];
    __syncthreads();
    float sum = 0.f;
    for (int k = tid; k < nv4; k += 256) {
        float4 f = row4[k];
        sum += expf(f.x - m) + expf(f.y - m) + expf(f.z - m) + expf(f.w - m);
    }
    for (int k = nv4 * 4 + tid; k < nv; k += 256) sum += expf(row[k] - m);
    red[tid] = sum;
    __syncthreads();
    for (int ss = 128; ss; ss >>= 1) {
        if (tid < ss) red[tid] += red[tid + ss];
        __syncthreads();
    }
    const float inv = 1.f / red[0];
    for (int k = tid; k < nv4; k += 256) {
        float4 f = row4[k];
        short4v o;
        o[0] = (short)f2b(expf(f.x - m) * inv);
        o[1] = (short)f2b(expf(f.y - m) * inv);
        o[2] = (short)f2b(expf(f.z - m) * inv);
        o[3] = (short)f2b(expf(f.w - m) * inv);
        *(short4v*)(arow + k * 4) = o;
    }
    for (int k = nv4 * 4 + tid; k < nv; k += 256) arow[k] = f2b(expf(row[k] - m) * inv);
    const int lim = ((i >> 7) + 1) << 7;   // pad to tile boundary for k_pv
    for (int k = nv + tid; k < lim; k += 256) arow[k] = 0;
}

// ---- pv: attno = attn @ vc (via vcT), pipelined single-precision ----------------
struct SPV { short8 a0, a1, b0; };
__global__ __launch_bounds__(256) void k_pv(const ushort_t* __restrict__ attn,
                                            const ushort_t* __restrict__ vcT,
                                            ushort_t* __restrict__ attno, int g0) {
    const int byi = blockIdx.x, z = blockIdx.y, hh = g0 + z;
    const int b = hh >> 3, h = hh & 7;
    __shared__ __align__(16) ushort_t lds[2][6144];
    const int l = threadIdx.x & 63, w = threadIdx.x >> 6;
    const int mb = w * 32;
    const ushort_t* ap = attn + (size_t)z * 4194304 + (size_t)(byi * 128) * 2048;
    const ushort_t* vp = vcT + (size_t)hh * 131072;
    const int nt = (byi + 1) * 4;
    const int tid = threadIdx.x;
    const int ra = tid >> 1, ca = (tid & 1) * 2;
    const int rb = tid >> 2, cb = tid & 3;
    SPV s;
    s.a0 = *(const short8*)(ap + (size_t)ra * 2048 + ca * 8);
    s.a1 = *(const short8*)(ap + (size_t)ra * 2048 + ca * 8 + 8);
    s.b0 = *(const short8*)(vp + (size_t)rb * 2048 + cb * 8);
    f32x4 acc[2][4] = {};
    for (int t = 0; t < nt; ++t) {
        ushort_t* buf = lds[t & 1];
        const int o0 = swz_off(ra, ca), o1 = swz_off(ra, ca + 1);
        *(short8*)(buf + o0) = s.a0;
        *(short8*)(buf + o1) = s.a1;
        *(short8*)(buf + 4096 + swz_off(rb, cb)) = s.b0;
        __syncthreads();
        if (t + 1 < nt) {
            int k0 = (t + 1) * 32;
            s.a0 = *(const short8*)(ap + (size_t)ra * 2048 + k0 + ca * 8);
            s.a1 = *(const short8*)(ap + (size_t)ra * 2048 + k0 + ca * 8 + 8);
            s.b0 = *(const short8*)(vp + (size_t)rb * 2048 + k0 + cb * 8);
        }
        short8 fa[2], fb[4];
#pragma unroll
        for (int i = 0; i < 2; ++i) fa[i] = sfrag(buf, mb + i * 16, l);
#pragma unroll
        for (int j = 0; j < 4; ++j) fb[j] = sfrag(buf + 4096, j * 16, l);
#pragma unroll
        for (int i = 0; i < 2; ++i)
#pragma unroll
            for (int j = 0; j < 4; ++j) acc[i][j] = MFMA16(fa[i], fb[j], acc[i][j]);
    }
#pragma unroll
    for (int i = 0; i < 2; ++i)
#pragma unroll
        for (int j = 0; j < 4; ++j)
#pragma unroll
            for (int r = 0; r < 4; ++r) {
                int gi = byi * 128 + mb + i * 16 + (l >> 4) * 4 + r;
                int d = j * 16 + (l & 15);
                attno[((size_t)(b * 2048 + gi)) * 512 + h * 64 + d] = f2b(acc[i][j][r]);
            }
}

// ---- final = attno @ Wout^T, pipelined single -----------------------------------
struct SO { short8 a0, a1, b0, b1; };
__global__ __launch_bounds__(256) void k_outproj(const ushort_t* __restrict__ attno,
                                                 const ushort_t* __restrict__ woh,
                                                 float* __restrict__ out) {
    __shared__ __align__(16) ushort_t lds[2][8192];
    const int m0 = blockIdx.y * 128, n0 = blockIdx.x * 128;
    const int l = threadIdx.x & 63, w = threadIdx.x >> 6;
    const int mb = (w >> 1) * 64, nb = (w & 1) * 64;
    const int tid = threadIdx.x, row = tid >> 1, c0 = (tid & 1) * 2;
    const ushort_t* pa = attno + (size_t)m0 * DI + (size_t)row * DI + c0 * 8;
    const ushort_t* pb = woh + (size_t)n0 * DI + (size_t)row * DI + c0 * 8;
    SO s;
    s.a0 = *(const short8*)pa; s.a1 = *(const short8*)(pa + 8);
    s.b0 = *(const short8*)pb; s.b1 = *(const short8*)(pb + 8);
    f32x4 acc[4][4] = {};
    for (int t = 0; t < 16; ++t) {
        ushort_t* buf = lds[t & 1];
        const int o0 = swz_off(row, c0), o1 = swz_off(row, c0 + 1);
        *(short8*)(buf + o0) = s.a0;        *(short8*)(buf + o1) = s.a1;
        *(short8*)(buf + 4096 + o0) = s.b0; *(short8*)(buf + 4096 + o1) = s.b1;
        __syncthreads();
        if (t + 1 < 16) {
            int k0 = (t + 1) * 32;
            s.a0 = *(const short8*)(pa + k0); s.a1 = *(const short8*)(pa + k0 + 8);
            s.b0 = *(const short8*)(pb + k0); s.b1 = *(const short8*)(pb + k0 + 8);
        }
        short8 fa[4], fb[4];
#pragma unroll
        for (int i = 0; i < 4; ++i) fa[i] = sfrag(buf, mb + i * 16, l);
#pragma unroll
        for (int j = 0; j < 4; ++j) fb[j] = sfrag(buf + 4096, nb + j * 16, l);
#pragma unroll
        for (int i = 0; i < 4; ++i)
#pragma unroll
            for (int j = 0; j < 4; ++j) acc[i][j] = MFMA16(fa[i], fb[j], acc[i][j]);
    }
#pragma unroll
    for (int i = 0; i < 4; ++i)
#pragma unroll
        for (int j = 0; j < 4; ++j)
#pragma unroll
            for (int r = 0; r < 4; ++r) {
                int m = m0 + mb + i * 16 + (l >> 4) * 4 + r;
                int n = n0 + nb + j * 16 + (l & 15);
                out[(size_t)m * DM + n] = acc[i][j][r];
            }
}

extern "C" void kernel_launch(void* const* d_in, const int* in_sizes, int n_in,
                              void* d_out, int out_size, void* d_ws, size_t ws_size,
                              hipStream_t stream) {
    const float* x = (const float*)d_in[0];
    const float* Wqkv = (const float*)d_in[1];
    const float* Wout = (const float*)d_in[2];
    float* out = (float*)d_out;

    const size_t fixedb = 58720256ull;   // qh + ql + vcT + attno (bytes)
    const size_t perh = 50331648ull;     // t1 h/l + look h/l + sc (bytes per head)
    int g = 0;
    for (int cand : {16, 8, 4, 2, 1})
        if (fixedb + perh * (size_t)cand <= ws_size) { g = cand; break; }
    if (!g) return;

    ushort_t* qh = (ushort_t*)d_ws;          // 12,582,912 el
    ushort_t* ql = qh + 12582912;            // 12,582,912 el
    ushort_t* vcT = ql + 12582912;           // 2,097,152 el
    ushort_t* attno = vcT + 2097152;         // 2,097,152 el
    ushort_t* pool = attno + 2097152;
    // cvt/proj phase aliases (dead after k_proj):
    ushort_t* xh = pool;                     // 4,194,304
    ushort_t* xl = xh + 4194304;             // 4,194,304
    ushort_t* wh = xl + 4194304;             // 3,145,728
    ushort_t* wl = wh + 3145728;             // 3,145,728  (total 29.4MB <= per-head pool)
    // group phase:
    ushort_t* t1h = pool;
    ushort_t* t1l = t1h + (size_t)g * 4194304;
    ushort_t* lkh = t1l + (size_t)g * 4194304;
    ushort_t* lkl = lkh + (size_t)g * 4194304;
    float* scb = (float*)(lkl + (size_t)g * 4194304);
    // outproj phase:
    ushort_t* woh = pool;

    k_cvt<<<dim3(1024), 256, 0, stream>>>((const float4*)x, xh, xl, 1048576, 1);
    k_cvt<<<dim3(1024), 256, 0, stream>>>((const float4*)Wqkv, wh, wl, 786432, 1);
    k_proj<<<dim3(24, 32), 256, 0, stream>>>(xh, xl, wh, wl, qh, ql, vcT);

    for (int g0 = 0; g0 < 16; g0 += g) {
        k_tl<<<dim3(16, 16, 2 * g), 256, 0, stream>>>(qh, ql, t1h, t1l, lkh, lkl, g0);
        k_scores<<<dim3(16, 16, g), 256, 0, stream>>>(t1h, t1l, lkh, lkl, qh, ql, scb, g0);
        k_softmax<<<dim3(2048 * g), 256, 0, stream>>>(scb, t1h);
        k_pv<<<dim3(16, g), 256, 0, stream>>>(t1h, vcT, attno, g0);
    }

    k_cvt<<<dim3(512), 256, 0, stream>>>((const float4*)Wout, woh, nullptr, 131072, 0);
    k_outproj<<<dim3(8, 32), 256, 0, stream>>>(attno, woh, out);
}